// Round 8
// baseline (192.524 us; speedup 1.0000x reference)
//
#include <hip/hip_runtime.h>

// RegionAttention: bf16 MFMA everywhere. Attention waves split along j (each
// wave owns all 64 q x its own 16 j): K/V LDS reads 1x, 1 barrier/tile.
// PV uses zero-padded 16x16x32 MFMA (the only MFMA verified this session):
// P regrouped 4->8 j/lane via ds_bpermute; lanes kgrp>=2 provide K zero-pad.
// q is PRE-SCALED by 0.125*log2(e); softmax has no max-subtract (bounded logits).

using bf16x8 = __attribute__((ext_vector_type(8))) short;
using f32x4  = __attribute__((ext_vector_type(4))) float;

__device__ __forceinline__ unsigned short f2bf(float f) {
    unsigned u = __float_as_uint(f);
    u += 0x7fff + ((u >> 16) & 1);
    return (unsigned short)(u >> 16);
}
__device__ __forceinline__ unsigned cvtpk(float lo, float hi) {
    unsigned r;
    asm("v_cvt_pk_bf16_f32 %0, %1, %2" : "=v"(r) : "v"(lo), "v"(hi));
    return r;
}
__device__ __forceinline__ void gload16(const void* g, void* l) {
    __builtin_amdgcn_global_load_lds(
        (const __attribute__((address_space(1))) void*)g,
        (__attribute__((address_space(3))) void*)l, 16, 0, 0);
}
__device__ __forceinline__ int l_from_rn(int region, int n) {
    int gi = region >> 2, gj = region & 3;
    int a = n >> 5, b = n & 31;
    return ((gi * 32 + a) << 7) + (gj << 5) + b;
}

// ---------------- cast kernels ----------------
__global__ __launch_bounds__(256) void cast_x_kernel(
    const float* __restrict__ x, unsigned short* __restrict__ xb)
{
    int tid = threadIdx.x;
    int t = blockIdx.x * 4 + (tid >> 6);
    int c8 = tid & 63;
    int l = l_from_rn(t >> 10, t & 1023);
    const float* src = x + (size_t)l * 512 + c8 * 8;
    float4 a = *(const float4*)src;
    float4 b = *(const float4*)(src + 4);
    bf16x8 o;
    o[0] = (short)f2bf(a.x); o[1] = (short)f2bf(a.y);
    o[2] = (short)f2bf(a.z); o[3] = (short)f2bf(a.w);
    o[4] = (short)f2bf(b.x); o[5] = (short)f2bf(b.y);
    o[6] = (short)f2bf(b.z); o[7] = (short)f2bf(b.w);
    *(bf16x8*)(xb + (size_t)t * 512 + c8 * 8) = o;
}

__global__ __launch_bounds__(256) void cast_w_kernel(
    const float* __restrict__ w, unsigned short* __restrict__ wb)
{
    int g = blockIdx.x * 256 + threadIdx.x;
    const float* src = w + (size_t)g * 8;
    float4 a = *(const float4*)src;
    float4 b = *(const float4*)(src + 4);
    bf16x8 o;
    o[0] = (short)f2bf(a.x); o[1] = (short)f2bf(a.y);
    o[2] = (short)f2bf(a.z); o[3] = (short)f2bf(a.w);
    o[4] = (short)f2bf(b.x); o[5] = (short)f2bf(b.y);
    o[6] = (short)f2bf(b.z); o[7] = (short)f2bf(b.w);
    *(bf16x8*)(wb + (size_t)g * 8) = o;
}

// ---------------- Kernel 1: QKV GEMM (bf16 MFMA) ----------------
__global__ __launch_bounds__(256) void qkv_kernel(
    const unsigned short* __restrict__ xb, const unsigned short* __restrict__ wb,
    const float* __restrict__ bias, unsigned short* __restrict__ qo,
    unsigned short* __restrict__ ko, unsigned short* __restrict__ vto)
{
    __shared__ __align__(16) unsigned short As[128 * 64];
    __shared__ __align__(16) unsigned short Bs[128 * 64];
    const int c0t = blockIdx.x * 128;
    const int t0 = blockIdx.y * 128;
    const int tid = threadIdx.x;
    const int lane = tid & 63, w = tid >> 6;
    const int arow = lane & 15, kgrp = lane >> 4;
    const int wr = w >> 1, wc = w & 1;

    f32x4 acc[4][4];
    #pragma unroll
    for (int m = 0; m < 4; ++m)
        #pragma unroll
        for (int n = 0; n < 4; ++n) {
            f32x4 z = {0.f, 0.f, 0.f, 0.f};
            acc[m][n] = z;
        }

    for (int k0 = 0; k0 < 512; k0 += 64) {
        __syncthreads();
        #pragma unroll
        for (int it = 0; it < 4; ++it) {
            int slot = it * 256 + tid;
            int row = slot >> 3, phys = slot & 7;
            int c8 = phys ^ (row & 7);
            gload16(xb + (size_t)(t0 + row) * 512 + k0 + c8 * 8,
                    &As[(it * 256 + (w << 6)) * 8]);
            gload16(wb + (size_t)(c0t + row) * 512 + k0 + c8 * 8,
                    &Bs[(it * 256 + (w << 6)) * 8]);
        }
        __syncthreads();

        bf16x8 af[4][2], bfr[4][2];
        #pragma unroll
        for (int m = 0; m < 4; ++m) {
            int r = wr * 64 + m * 16 + arow;
            af[m][0] = *(const bf16x8*)&As[r * 64 + ((kgrp ^ (r & 7)) * 8)];
            af[m][1] = *(const bf16x8*)&As[r * 64 + (((4 + kgrp) ^ (r & 7)) * 8)];
        }
        #pragma unroll
        for (int n = 0; n < 4; ++n) {
            int r = wc * 64 + n * 16 + arow;
            bfr[n][0] = *(const bf16x8*)&Bs[r * 64 + ((kgrp ^ (r & 7)) * 8)];
            bfr[n][1] = *(const bf16x8*)&Bs[r * 64 + (((4 + kgrp) ^ (r & 7)) * 8)];
        }
        #pragma unroll
        for (int m = 0; m < 4; ++m)
            #pragma unroll
            for (int n = 0; n < 4; ++n) {
                acc[m][n] = __builtin_amdgcn_mfma_f32_16x16x32_bf16(
                    af[m][0], bfr[n][0], acc[m][n], 0, 0, 0);
                acc[m][n] = __builtin_amdgcn_mfma_f32_16x16x32_bf16(
                    af[m][1], bfr[n][1], acc[m][n], 0, 0, 0);
            }
    }

    const int s = c0t >> 9;
    const int region = t0 >> 10;
    const float qs = (s == 0) ? 0.18033688f : 1.0f;
    #pragma unroll
    for (int n = 0; n < 4; ++n) {
        int cg = c0t + wc * 64 + n * 16 + arow;
        float bi = bias[cg];
        int h = (cg >> 6) & 7, d = cg & 63;
        if (s < 2) {
            unsigned short* dst = (s == 0) ? qo : ko;
            #pragma unroll
            for (int m = 0; m < 4; ++m) {
                int tb = t0 + wr * 64 + m * 16 + kgrp * 4;
                unsigned short* p =
                    dst + ((size_t)(region * 8 + h) * 1024 + (tb & 1023)) * 64 + d;
                #pragma unroll
                for (int i = 0; i < 4; ++i)
                    p[(size_t)i * 64] = f2bf((acc[m][n][i] + bi) * qs);
            }
        } else {
            #pragma unroll
            for (int m = 0; m < 4; ++m) {
                int tb = t0 + wr * 64 + m * 16 + kgrp * 4;
                ushort4 pk;
                pk.x = f2bf(acc[m][n][0] + bi);
                pk.y = f2bf(acc[m][n][1] + bi);
                pk.z = f2bf(acc[m][n][2] + bi);
                pk.w = f2bf(acc[m][n][3] + bi);
                *(ushort4*)(vto + (size_t)(region * 8 + h) * 65536 +
                            (size_t)d * 1024 + (tb & 1023)) = pk;
            }
        }
    }
}

// ---------------- Kernel 2: all-MFMA attention, j-split waves ----------------
__global__ __launch_bounds__(256) void attn_kernel(
    const unsigned short* __restrict__ qg, const unsigned short* __restrict__ kg,
    const unsigned short* __restrict__ vtg, const float* __restrict__ epw,
    const float* __restrict__ epb, unsigned short* __restrict__ ao)
{
    const int rb = blockIdx.x, head = blockIdx.y, region = blockIdx.z;
    const int rh = region * 8 + head;
    const unsigned short* qb = qg + (size_t)rh * 65536;
    const unsigned short* kb = kg + (size_t)rh * 65536;
    const unsigned short* vb = vtg + (size_t)rh * 65536;
    const int i0 = rb * 64;
    const int tid = threadIdx.x;
    const int lane = tid & 63, wj = tid >> 6;
    const int arow = lane & 15, kgrp = lane >> 4;

    // smem: Ks[2][4096]sh | VTs[2][4096]sh | ST2 64x176B | row_lw[4][64]f
    __shared__ __align__(16) unsigned char smem[45056];
    unsigned short* const Ks  = (unsigned short*)smem;
    unsigned short* const VTs = (unsigned short*)(smem + 16384);
    char* const st2b = (char*)(smem + 32768);
    float* const row_lw = (float*)(smem + 44032);

    // zero ST2 pad regions: bytes 0..3 (q=-4,-3) and 140..175 (q>=66) per row
    for (int idx = tid; idx < 640; idx += 256) {
        int j = idx / 10, sl = idx % 10;
        int off = (sl == 0) ? 0 : (136 + sl * 4);
        *(unsigned*)(st2b + j * 176 + off) = 0u;
    }

    // Q fragments: 4 q-groups x 2 k-halves (pre-scaled)
    bf16x8 qf[4][2];
    #pragma unroll
    for (int m = 0; m < 4; ++m) {
        const unsigned short* p = qb + (size_t)(i0 + m * 16 + arow) * 64 + kgrp * 8;
        qf[m][0] = *(const bf16x8*)p;
        qf[m][1] = *(const bf16x8*)(p + 32);
    }
    // halo Q: A-rows 0..3 = q {i0-2,i0-1,i0+64,i0+65}, rest zero
    bf16x8 qhf0, qhf1;
    #pragma unroll
    for (int e = 0; e < 8; ++e) { qhf0[e] = 0; qhf1[e] = 0; }
    {
        int gi = (arow < 2) ? (i0 - 2 + arow) : (i0 + 62 + arow);
        if (arow < 4 && gi >= 0 && gi < 1024) {
            const unsigned short* p = qb + (size_t)gi * 64 + kgrp * 8;
            qhf0 = *(const bf16x8*)p;
            qhf1 = *(const bf16x8*)(p + 32);
        }
    }

    // band fragment: B[k=kgrp*8+e][n=arow] = cwt[k-n-2]
    bf16x8 bandf;
    {
        float cwt[5];
        #pragma unroll
        for (int t = 0; t < 5; ++t) cwt[t] = epw[head * 5 + t];
        cwt[2] += 1.0f;
        #pragma unroll
        for (int e = 0; e < 8; ++e) {
            int c = kgrp * 8 + e - arow - 2;
            float v = 0.f;
            v = (c == 0) ? cwt[0] : v;
            v = (c == 1) ? cwt[1] : v;
            v = (c == 2) ? cwt[2] : v;
            v = (c == 3) ? cwt[3] : v;
            v = (c == 4) ? cwt[4] : v;
            bandf[e] = (short)f2bf(v);
        }
    }

    f32x4 oacc[4][4];
    #pragma unroll
    for (int iw = 0; iw < 4; ++iw)
        #pragma unroll
        for (int dt = 0; dt < 4; ++dt) {
            f32x4 z = {0.f, 0.f, 0.f, 0.f};
            oacc[iw][dt] = z;
        }
    float lp[4] = {0.f, 0.f, 0.f, 0.f};

    // bpermute sources for the 4->8 j regroup (kgrp'=kgrp<2 merges pairs)
    const int sA = arow + ((kgrp & 1) << 5);
    const int sB = sA + 16;
    const bool hipad = (kgrp >= 2);

    auto stage = [&](int jt, int buf) {
        const int j0 = jt * 64;
        #pragma unroll
        for (int it = 0; it < 2; ++it) {
            int q_ = (it * 4 + wj) * 64 + lane;
            int row = q_ >> 3, phys = q_ & 7, c8 = phys ^ (row & 7);
            gload16(kb + (size_t)(j0 + row) * 64 + c8 * 8,
                    &Ks[buf * 4096 + (it * 4 + wj) * 512]);
            gload16(vb + (size_t)row * 1024 + j0 + c8 * 8,
                    &VTs[buf * 4096 + (it * 4 + wj) * 512]);
        }
    };

    stage(0, 0);

    for (int jt = 0; jt < 16; ++jt) {
        const int cur = jt & 1;
        __syncthreads();   // staged tile landed (vmcnt drained); bufs reusable
        if (jt < 15) stage(jt + 1, cur ^ 1);

        const unsigned short* Kc = Ks + cur * 4096;
        const unsigned short* Vc = VTs + cur * 4096;
        const int krow = wj * 16 + arow;   // wave-own j row
        bf16x8 kf0 = *(const bf16x8*)&Kc[krow * 64 + ((kgrp ^ (krow & 7)) * 8)];
        bf16x8 kf1 = *(const bf16x8*)&Kc[krow * 64 + (((4 + kgrp) ^ (krow & 7)) * 8)];
        // hoisted V B-fragments (K=32): element group wj*16 + (kgrp&1)*8
        bf16x8 vf[4];
        #pragma unroll
        for (int dt = 0; dt < 4; ++dt) {
            const int drow = dt * 16 + arow;
            const int slot = (wj * 2 + (kgrp & 1)) ^ (drow & 7);
            vf[dt] = *(const bf16x8*)((const char*)Vc + drow * 128 + (slot << 4));
        }
        char* const srow = st2b + krow * 176;

        // QK: S^T[j=krow][q], q = m*16 + kgrp*4 + reg  (wave-private rows)
        #pragma unroll
        for (int m = 0; m < 4; ++m) {
            f32x4 sacc = {0.f, 0.f, 0.f, 0.f};
            sacc = __builtin_amdgcn_mfma_f32_16x16x32_bf16(qf[m][0], kf0, sacc, 0, 0, 0);
            sacc = __builtin_amdgcn_mfma_f32_16x16x32_bf16(qf[m][1], kf1, sacc, 0, 0, 0);
            uint2 uu;
            uu.x = cvtpk(sacc[0], sacc[1]);
            uu.y = cvtpk(sacc[2], sacc[3]);
            *(uint2*)(srow + 8 + m * 32 + kgrp * 8) = uu;
        }
        // halo rows: q=-2,-1 at bytes 4..7; q=64,65 at bytes 136..139
        {
            f32x4 hacc = {0.f, 0.f, 0.f, 0.f};
            hacc = __builtin_amdgcn_mfma_f32_16x16x32_bf16(qhf0, kf0, hacc, 0, 0, 0);
            hacc = __builtin_amdgcn_mfma_f32_16x16x32_bf16(qhf1, kf1, hacc, 0, 0, 0);
            if (kgrp == 0) {
                *(unsigned*)(srow + 4)   = cvtpk(hacc[0], hacc[1]);
                *(unsigned*)(srow + 136) = cvtpk(hacc[2], hacc[3]);
            }
        }
        // pin ds_write -> ds_read order (TBAA: stores/loads of different
        // vector types don't alias) and drain the per-wave LDS queue.
        asm volatile("s_waitcnt lgkmcnt(0)" ::: "memory");
        __builtin_amdgcn_sched_barrier(0);

        // conv (banded MFMA) -> p=exp2 -> regroup 4->8 j -> PV (K=32, padded)
        #pragma unroll
        for (int iw = 0; iw < 4; ++iw) {
            bf16x8 saf = *(const bf16x8*)(srow + iw * 32 + kgrp * 16);
            f32x4 z = {0.f, 0.f, 0.f, 0.f};
            z = __builtin_amdgcn_mfma_f32_16x16x32_bf16(saf, bandf, z, 0, 0, 0);
            float p0 = exp2f(z[0]), p1 = exp2f(z[1]);
            float p2 = exp2f(z[2]), p3 = exp2f(z[3]);
            lp[iw] += (p0 + p1) + (p2 + p3);
            unsigned u0 = cvtpk(p0, p1);
            unsigned u1 = cvtpk(p2, p3);
            unsigned y0 = (unsigned)__shfl((int)u0, sA);
            unsigned y1 = (unsigned)__shfl((int)u1, sA);
            unsigned y2 = (unsigned)__shfl((int)u0, sB);
            unsigned y3 = (unsigned)__shfl((int)u1, sB);
            union { unsigned u[4]; bf16x8 v; } pa;
            pa.u[0] = hipad ? 0u : y0;
            pa.u[1] = hipad ? 0u : y1;
            pa.u[2] = hipad ? 0u : y2;
            pa.u[3] = hipad ? 0u : y3;
            #pragma unroll
            for (int dt = 0; dt < 4; ++dt)
                oacc[iw][dt] = __builtin_amdgcn_mfma_f32_16x16x32_bf16(
                    pa.v, vf[dt], oacc[iw][dt], 0, 0, 0);
        }
    }

    // row-sum partials: reduce over kgrp, store per-wave
    #pragma unroll
    for (int iw = 0; iw < 4; ++iw) {
        float s = lp[iw];
        s += __shfl_xor(s, 16);
        s += __shfl_xor(s, 32);
        if (kgrp == 0) row_lw[wj * 64 + iw * 16 + arow] = s;
    }
    __syncthreads();   // all tiles done; staging LDS reusable as scratch

    // cross-wave oacc reduction through 32KB scratch
    float* const scr = (float*)smem;
    if (wj >= 2) {
        float* d = scr + (wj - 2) * 4096;
        #pragma unroll
        for (int iw = 0; iw < 4; ++iw)
            #pragma unroll
            for (int dt = 0; dt < 4; ++dt)
                *(f32x4*)&d[(iw * 4 + dt) * 256 + lane * 4] = oacc[iw][dt];
    }
    __syncthreads();
    if (wj < 2) {
        const float* s = scr + wj * 4096;
        #pragma unroll
        for (int iw = 0; iw < 4; ++iw)
            #pragma unroll
            for (int dt = 0; dt < 4; ++dt)
                oacc[iw][dt] += *(const f32x4*)&s[(iw * 4 + dt) * 256 + lane * 4];
    }
    __syncthreads();
    if (wj == 1) {
        #pragma unroll
        for (int iw = 0; iw < 4; ++iw)
            #pragma unroll
            for (int dt = 0; dt < 4; ++dt)
                *(f32x4*)&scr[(iw * 4 + dt) * 256 + lane * 4] = oacc[iw][dt];
    }
    __syncthreads();
    if (wj == 0) {
        #pragma unroll
        for (int iw = 0; iw < 4; ++iw)
            #pragma unroll
            for (int dt = 0; dt < 4; ++dt) {
                oacc[iw][dt] += *(const f32x4*)&scr[(iw * 4 + dt) * 256 + lane * 4];
                *(f32x4*)&scr[(iw * 4 + dt) * 256 + lane * 4] = oacc[iw][dt];
            }
    }
    __syncthreads();

    // cooperative normalize + coalesced bf16 store
    {
        const int q = tid >> 2, dseg = tid & 3;
        float invq = 1.f / (row_lw[q] + row_lw[64 + q] +
                            row_lw[128 + q] + row_lw[192 + q]);
        const int base = ((q >> 4) * 4 + dseg) * 256 + ((q >> 2) & 3) * 64 + (q & 3);
        float f[16];
        #pragma unroll
        for (int e = 0; e < 16; ++e) f[e] = scr[base + e * 4] * invq;
        uint4 oA, oB;
        oA.x = cvtpk(f[0], f[1]);  oA.y = cvtpk(f[2], f[3]);
        oA.z = cvtpk(f[4], f[5]);  oA.w = cvtpk(f[6], f[7]);
        oB.x = cvtpk(f[8], f[9]);  oB.y = cvtpk(f[10], f[11]);
        oB.z = cvtpk(f[12], f[13]); oB.w = cvtpk(f[14], f[15]);
        unsigned short* op = ao + (size_t)(region * 1024 + i0 + q) * 512 +
                             head * 64 + dseg * 16;
        *(uint4*)op = oA;
        *(uint4*)(op + 8) = oB;
    }
}

// ---------------- Kernel 3: proj GEMM (bf16 MFMA, fp32 out, un-permute) -------------
__global__ __launch_bounds__(256) void proj_kernel(
    const unsigned short* __restrict__ ab, const unsigned short* __restrict__ wb,
    const float* __restrict__ bias, float* __restrict__ out)
{
    __shared__ __align__(16) unsigned short As[128 * 64];
    __shared__ __align__(16) unsigned short Bs[128 * 64];
    const int c0t = blockIdx.x * 128;
    const int t0 = blockIdx.y * 128;
    const int tid = threadIdx.x;
    const int lane = tid & 63, w = tid >> 6;
    const int arow = lane & 15, kgrp = lane >> 4;
    const int wr = w >> 1, wc = w & 1;

    f32x4 acc[4][4];
    #pragma unroll
    for (int m = 0; m < 4; ++m)
        #pragma unroll
        for (int n = 0; n < 4; ++n) {
            f32x4 z = {0.f, 0.f, 0.f, 0.f};
            acc[m][n] = z;
        }

    for (int k0 = 0; k0 < 512; k0 += 64) {
        __syncthreads();
        #pragma unroll
        for (int it = 0; it < 4; ++it) {
            int slot = it * 256 + tid;
            int row = slot >> 3, phys = slot & 7;
            int c8 = phys ^ (row & 7);
            gload16(ab + (size_t)(t0 + row) * 512 + k0 + c8 * 8,
                    &As[(it * 256 + (w << 6)) * 8]);
            gload16(wb + (size_t)(c0t + row) * 512 + k0 + c8 * 8,
                    &Bs[(it * 256 + (w << 6)) * 8]);
        }
        __syncthreads();

        bf16x8 af[4][2], bfr[4][2];
        #pragma unroll
        for (int m = 0; m < 4; ++m) {
            int r = wr * 64 + m * 16 + arow;
            af[m][0] = *(const bf16x8*)&As[r * 64 + ((kgrp ^ (r & 7)) * 8)];
            af[m][1] = *(const bf16x8*)&As[r * 64 + (((4 + kgrp) ^ (r & 7)) * 8)];
        }
        #pragma unroll
        for (int n = 0; n < 4; ++n) {
            int r = wc * 64 + n * 16 + arow;
            bfr[n][0] = *(const bf16x8*)&Bs[r * 64 + ((kgrp ^ (r & 7)) * 8)];
            bfr[n][1] = *(const bf16x8*)&Bs[r * 64 + (((4 + kgrp) ^ (r & 7)) * 8)];
        }
        #pragma unroll
        for (int m = 0; m < 4; ++m)
            #pragma unroll
            for (int n = 0; n < 4; ++n) {
                acc[m][n] = __builtin_amdgcn_mfma_f32_16x16x32_bf16(
                    af[m][0], bfr[n][0], acc[m][n], 0, 0, 0);
                acc[m][n] = __builtin_amdgcn_mfma_f32_16x16x32_bf16(
                    af[m][1], bfr[n][1], acc[m][n], 0, 0, 0);
            }
    }

    #pragma unroll
    for (int n = 0; n < 4; ++n) {
        int cg = c0t + wc * 64 + n * 16 + arow;
        float bi = bias[cg];
        #pragma unroll
        for (int m = 0; m < 4; ++m) {
            int tb = t0 + wr * 64 + m * 16 + kgrp * 4;
            int l0 = l_from_rn(tb >> 10, tb & 1023);
            float* p = out + (size_t)l0 * 512 + cg;
            #pragma unroll
            for (int i = 0; i < 4; ++i)
                p[(size_t)i * 512] = acc[m][n][i] + bi;
        }
    }
}

extern "C" void kernel_launch(void* const* d_in, const int* in_sizes, int n_in,
                              void* d_out, int out_size, void* d_ws, size_t ws_size,
                              hipStream_t stream) {
    const float* x      = (const float*)d_in[0];
    const float* qkv_w  = (const float*)d_in[1];
    const float* qkv_b  = (const float*)d_in[2];
    const float* proj_w = (const float*)d_in[3];
    const float* proj_b = (const float*)d_in[4];
    const float* epeg_w = (const float*)d_in[5];
    const float* epeg_b = (const float*)d_in[6];
    float* out = (float*)d_out;

    const size_t NTOK = (size_t)16384 * 512;
    unsigned short* xb    = (unsigned short*)d_ws;
    unsigned short* wqkv  = xb + NTOK;
    unsigned short* wproj = wqkv + (size_t)1536 * 512;
    unsigned short* qb    = wproj + (size_t)512 * 512;
    unsigned short* kb    = qb + NTOK;
    unsigned short* vtb   = kb + NTOK;
    unsigned short* ao    = vtb + NTOK;

    cast_x_kernel<<<4096, 256, 0, stream>>>(x, xb);
    cast_w_kernel<<<384, 256, 0, stream>>>(qkv_w, wqkv);
    cast_w_kernel<<<128, 256, 0, stream>>>(proj_w, wproj);
    {
        dim3 grid(12, 128);
        qkv_kernel<<<grid, 256, 0, stream>>>(xb, wqkv, qkv_b, qb, kb, vtb);
    }
    {
        dim3 grid(16, 8, 16);
        attn_kernel<<<grid, 256, 0, stream>>>(qb, kb, vtb, epeg_w, epeg_b, ao);
    }
    {
        dim3 grid(4, 128);
        proj_kernel<<<grid, 256, 0, stream>>>(ao, wproj, proj_b, out);
    }
}

// Round 9
// 166.975 us; speedup vs baseline: 1.1530x; 1.1530x over previous
//
#include <hip/hip_runtime.h>

// RegionAttention: bf16 MFMA everywhere; attention uses MFMA for QK, EPEG-conv
// (banded matmul), and PV; no-max softmax in exp2 domain; deferred row-sum.
// R9 = R5 structure + (a) ST2 stride 160->176B (4-way -> 2-way bank conflicts),
// (b) V fragments hoisted above the mid barrier (latency overlap),
// (c) sched_barrier(0) between P store and PV read (pin program order).
// q is PRE-SCALED by 0.125*log2(e).

using bf16x8 = __attribute__((ext_vector_type(8))) short;
using f32x4  = __attribute__((ext_vector_type(4))) float;

__device__ __forceinline__ unsigned short f2bf(float f) {
    unsigned u = __float_as_uint(f);
    u += 0x7fff + ((u >> 16) & 1);
    return (unsigned short)(u >> 16);
}
__device__ __forceinline__ unsigned cvtpk(float lo, float hi) {
    unsigned r;
    asm("v_cvt_pk_bf16_f32 %0, %1, %2" : "=v"(r) : "v"(lo), "v"(hi));
    return r;
}
__device__ __forceinline__ void gload16(const void* g, void* l) {
    __builtin_amdgcn_global_load_lds(
        (const __attribute__((address_space(1))) void*)g,
        (__attribute__((address_space(3))) void*)l, 16, 0, 0);
}
__device__ __forceinline__ int l_from_rn(int region, int n) {
    int gi = region >> 2, gj = region & 3;
    int a = n >> 5, b = n & 31;
    return ((gi * 32 + a) << 7) + (gj << 5) + b;
}

// ---------------- cast kernels ----------------
__global__ __launch_bounds__(256) void cast_x_kernel(
    const float* __restrict__ x, unsigned short* __restrict__ xb)
{
    int tid = threadIdx.x;
    int t = blockIdx.x * 4 + (tid >> 6);
    int c8 = tid & 63;
    int l = l_from_rn(t >> 10, t & 1023);
    const float* src = x + (size_t)l * 512 + c8 * 8;
    float4 a = *(const float4*)src;
    float4 b = *(const float4*)(src + 4);
    bf16x8 o;
    o[0] = (short)f2bf(a.x); o[1] = (short)f2bf(a.y);
    o[2] = (short)f2bf(a.z); o[3] = (short)f2bf(a.w);
    o[4] = (short)f2bf(b.x); o[5] = (short)f2bf(b.y);
    o[6] = (short)f2bf(b.z); o[7] = (short)f2bf(b.w);
    *(bf16x8*)(xb + (size_t)t * 512 + c8 * 8) = o;
}

__global__ __launch_bounds__(256) void cast_w_kernel(
    const float* __restrict__ w, unsigned short* __restrict__ wb)
{
    int g = blockIdx.x * 256 + threadIdx.x;
    const float* src = w + (size_t)g * 8;
    float4 a = *(const float4*)src;
    float4 b = *(const float4*)(src + 4);
    bf16x8 o;
    o[0] = (short)f2bf(a.x); o[1] = (short)f2bf(a.y);
    o[2] = (short)f2bf(a.z); o[3] = (short)f2bf(a.w);
    o[4] = (short)f2bf(b.x); o[5] = (short)f2bf(b.y);
    o[6] = (short)f2bf(b.z); o[7] = (short)f2bf(b.w);
    *(bf16x8*)(wb + (size_t)g * 8) = o;
}

// ---------------- Kernel 1: QKV GEMM (bf16 MFMA) ----------------
__global__ __launch_bounds__(256) void qkv_kernel(
    const unsigned short* __restrict__ xb, const unsigned short* __restrict__ wb,
    const float* __restrict__ bias, unsigned short* __restrict__ qo,
    unsigned short* __restrict__ ko, unsigned short* __restrict__ vto)
{
    __shared__ __align__(16) unsigned short As[128 * 64];
    __shared__ __align__(16) unsigned short Bs[128 * 64];
    const int c0t = blockIdx.x * 128;
    const int t0 = blockIdx.y * 128;
    const int tid = threadIdx.x;
    const int lane = tid & 63, w = tid >> 6;
    const int arow = lane & 15, kgrp = lane >> 4;
    const int wr = w >> 1, wc = w & 1;

    f32x4 acc[4][4];
    #pragma unroll
    for (int m = 0; m < 4; ++m)
        #pragma unroll
        for (int n = 0; n < 4; ++n) {
            f32x4 z = {0.f, 0.f, 0.f, 0.f};
            acc[m][n] = z;
        }

    for (int k0 = 0; k0 < 512; k0 += 64) {
        __syncthreads();
        #pragma unroll
        for (int it = 0; it < 4; ++it) {
            int slot = it * 256 + tid;
            int row = slot >> 3, phys = slot & 7;
            int c8 = phys ^ (row & 7);
            gload16(xb + (size_t)(t0 + row) * 512 + k0 + c8 * 8,
                    &As[(it * 256 + (w << 6)) * 8]);
            gload16(wb + (size_t)(c0t + row) * 512 + k0 + c8 * 8,
                    &Bs[(it * 256 + (w << 6)) * 8]);
        }
        __syncthreads();

        bf16x8 af[4][2], bfr[4][2];
        #pragma unroll
        for (int m = 0; m < 4; ++m) {
            int r = wr * 64 + m * 16 + arow;
            af[m][0] = *(const bf16x8*)&As[r * 64 + ((kgrp ^ (r & 7)) * 8)];
            af[m][1] = *(const bf16x8*)&As[r * 64 + (((4 + kgrp) ^ (r & 7)) * 8)];
        }
        #pragma unroll
        for (int n = 0; n < 4; ++n) {
            int r = wc * 64 + n * 16 + arow;
            bfr[n][0] = *(const bf16x8*)&Bs[r * 64 + ((kgrp ^ (r & 7)) * 8)];
            bfr[n][1] = *(const bf16x8*)&Bs[r * 64 + (((4 + kgrp) ^ (r & 7)) * 8)];
        }
        #pragma unroll
        for (int m = 0; m < 4; ++m)
            #pragma unroll
            for (int n = 0; n < 4; ++n) {
                acc[m][n] = __builtin_amdgcn_mfma_f32_16x16x32_bf16(
                    af[m][0], bfr[n][0], acc[m][n], 0, 0, 0);
                acc[m][n] = __builtin_amdgcn_mfma_f32_16x16x32_bf16(
                    af[m][1], bfr[n][1], acc[m][n], 0, 0, 0);
            }
    }

    const int s = c0t >> 9;
    const int region = t0 >> 10;
    // q pre-scale: 0.125 (attn scale) * log2(e) (exp2-domain softmax)
    const float qs = (s == 0) ? 0.18033688f : 1.0f;
    #pragma unroll
    for (int n = 0; n < 4; ++n) {
        int cg = c0t + wc * 64 + n * 16 + arow;
        float bi = bias[cg];
        int h = (cg >> 6) & 7, d = cg & 63;
        if (s < 2) {
            unsigned short* dst = (s == 0) ? qo : ko;
            #pragma unroll
            for (int m = 0; m < 4; ++m) {
                int tb = t0 + wr * 64 + m * 16 + kgrp * 4;
                unsigned short* p =
                    dst + ((size_t)(region * 8 + h) * 1024 + (tb & 1023)) * 64 + d;
                #pragma unroll
                for (int i = 0; i < 4; ++i)
                    p[(size_t)i * 64] = f2bf((acc[m][n][i] + bi) * qs);
            }
        } else {
            #pragma unroll
            for (int m = 0; m < 4; ++m) {
                int tb = t0 + wr * 64 + m * 16 + kgrp * 4;
                ushort4 pk;
                pk.x = f2bf(acc[m][n][0] + bi);
                pk.y = f2bf(acc[m][n][1] + bi);
                pk.z = f2bf(acc[m][n][2] + bi);
                pk.w = f2bf(acc[m][n][3] + bi);
                *(ushort4*)(vto + (size_t)(region * 8 + h) * 65536 +
                            (size_t)d * 1024 + (tb & 1023)) = pk;
            }
        }
    }
}

// ---------------- Kernel 2: all-MFMA attention (q-split waves, R5 base) -----------
__global__ __launch_bounds__(256) void attn_kernel(
    const unsigned short* __restrict__ qg, const unsigned short* __restrict__ kg,
    const unsigned short* __restrict__ vtg, const float* __restrict__ epw,
    const float* __restrict__ epb, unsigned short* __restrict__ ao)
{
    const int rb = blockIdx.x, head = blockIdx.y, region = blockIdx.z;
    const int rh = region * 8 + head;
    const unsigned short* qb = qg + (size_t)rh * 65536;
    const unsigned short* kb = kg + (size_t)rh * 65536;
    const unsigned short* vb = vtg + (size_t)rh * 65536;
    const int i0 = rb * 64;
    const int tid = threadIdx.x;
    const int lane = tid & 63, w = tid >> 6;
    const int arow = lane & 15, kgrp = lane >> 4;
    const int strow = w * 16 + arow;   // this thread's q-row (block-local)

    __shared__ __align__(16) unsigned short Ks[2][4096];
    __shared__ __align__(16) unsigned short VTs[2][4096];
    __shared__ __align__(16) unsigned short ST2[64 * 88]; // S^T [j][q], 176B rows
    __shared__ __align__(16) unsigned short Ps[4096];
    __shared__ float row_l[64];

    char* const st2b = (char*)ST2;
    // zero ST2 pad regions per row: bytes 0..3 (q=-4,-3) and 140..175 (q>=66)
    for (int idx = tid; idx < 640; idx += 256) {
        int j = idx / 10, sl = idx % 10;
        int off = (sl == 0) ? 0 : (136 + sl * 4);
        *(unsigned*)(st2b + j * 176 + off) = 0u;
    }

    // Q fragments (pre-scaled)
    bf16x8 qf0, qf1;
    {
        const unsigned short* p = qb + (size_t)(i0 + strow) * 64 + kgrp * 8;
        qf0 = *(const bf16x8*)p;
        qf1 = *(const bf16x8*)(p + 32);
    }
    // halo Q fragment: A-rows 0..3 = q rows {i0-2,i0-1,i0+64,i0+65}, rest zero
    bf16x8 qhf0, qhf1;
    #pragma unroll
    for (int e = 0; e < 8; ++e) { qhf0[e] = 0; qhf1[e] = 0; }
    {
        int gi = (arow < 2) ? (i0 - 2 + arow) : (i0 + 62 + arow);
        if (arow < 4 && gi >= 0 && gi < 1024) {
            const unsigned short* p = qb + (size_t)gi * 64 + kgrp * 8;
            qhf0 = *(const bf16x8*)p;
            qhf1 = *(const bf16x8*)(p + 32);
        }
    }

    // Band B-fragment (constant): B[k][n=arow] = cwt[k-n-2], k = kgrp*8+e
    bf16x8 bandf;
    {
        float cwt[5];
        #pragma unroll
        for (int t = 0; t < 5; ++t) cwt[t] = epw[head * 5 + t];
        cwt[2] += 1.0f;   // identity (direct S) term
        #pragma unroll
        for (int e = 0; e < 8; ++e) {
            int k = kgrp * 8 + e;
            int c = k - arow - 2;
            float v = 0.f;
            v = (c == 0) ? cwt[0] : v;
            v = (c == 1) ? cwt[1] : v;
            v = (c == 2) ? cwt[2] : v;
            v = (c == 3) ? cwt[3] : v;
            v = (c == 4) ? cwt[4] : v;
            bandf[e] = (short)f2bf(v);
        }
    }

    f32x4 oacc[4];
    #pragma unroll
    for (int dt = 0; dt < 4; ++dt) {
        f32x4 z = {0.f, 0.f, 0.f, 0.f};
        oacc[dt] = z;
    }
    float l_part = 0.f;

    auto stage = [&](int jt, int buf) {
        const int j0 = jt * 64;
        #pragma unroll
        for (int it = 0; it < 2; ++it) {
            int q_ = (it * 4 + w) * 64 + lane;
            int row = q_ >> 3, phys = q_ & 7, c8 = phys ^ (row & 7);
            gload16(kb + (size_t)(j0 + row) * 64 + c8 * 8,
                    &Ks[buf][(it * 4 + w) * 512]);
            gload16(vb + (size_t)row * 1024 + j0 + c8 * 8,
                    &VTs[buf][(it * 4 + w) * 512]);
        }
    };

    stage(0, 0);

    for (int jt = 0; jt < 16; ++jt) {
        const int cur = jt & 1;
        __syncthreads();   // staged tile landed; ST2/Ps reads of prev tile done
        if (jt < 15) stage(jt + 1, cur ^ 1);

        const unsigned short* Kc = &Ks[cur][0];
        const unsigned short* Vc = &VTs[cur][0];

        // hoisted V fragments (valid post-barrier; overlap QK/S^T phase)
        bf16x8 vf[4][2];
        #pragma unroll
        for (int dt = 0; dt < 4; ++dt) {
            int drow = dt * 16 + arow;
            vf[dt][0] = *(const bf16x8*)&Vc[drow * 64 + ((kgrp ^ (drow & 7)) * 8)];
            vf[dt][1] = *(const bf16x8*)&Vc[drow * 64 + (((4 + kgrp) ^ (drow & 7)) * 8)];
        }

        // QK -> S^T bf16 (rows j, cols q at byte 8+q*2); halo on ct==w
        #pragma unroll
        for (int ct = 0; ct < 4; ++ct) {
            f32x4 sacc = {0.f, 0.f, 0.f, 0.f};
            int krow = ct * 16 + arow;
            bf16x8 kf0 = *(const bf16x8*)&Kc[krow * 64 + ((kgrp ^ (krow & 7)) * 8)];
            bf16x8 kf1 = *(const bf16x8*)&Kc[krow * 64 + (((4 + kgrp) ^ (krow & 7)) * 8)];
            sacc = __builtin_amdgcn_mfma_f32_16x16x32_bf16(qf0, kf0, sacc, 0, 0, 0);
            sacc = __builtin_amdgcn_mfma_f32_16x16x32_bf16(qf1, kf1, sacc, 0, 0, 0);
            uint2 uu;
            uu.x = cvtpk(sacc[0], sacc[1]);
            uu.y = cvtpk(sacc[2], sacc[3]);
            *(uint2*)(st2b + krow * 176 + 8 + w * 32 + kgrp * 8) = uu;
            if (ct == w) {
                f32x4 hacc = {0.f, 0.f, 0.f, 0.f};
                hacc = __builtin_amdgcn_mfma_f32_16x16x32_bf16(qhf0, kf0, hacc, 0, 0, 0);
                hacc = __builtin_amdgcn_mfma_f32_16x16x32_bf16(qhf1, kf1, hacc, 0, 0, 0);
                if (kgrp == 0) {
                    *(unsigned*)(st2b + krow * 176 + 4)   = cvtpk(hacc[0], hacc[1]);
                    *(unsigned*)(st2b + krow * 176 + 136) = cvtpk(hacc[2], hacc[3]);
                }
            }
        }
        // S^T visible to all waves; prefetch stays in flight (no vmcnt drain)
        asm volatile("s_waitcnt lgkmcnt(0)\n\ts_barrier" ::: "memory");

        // conv via banded MFMA: D^T[j][q], q=arow lane-local; then exp2 + pack
        #pragma unroll
        for (int ct = 0; ct < 4; ++ct) {
            bf16x8 saf = *(const bf16x8*)(st2b + (ct * 16 + arow) * 176 +
                                          w * 32 + kgrp * 16);
            f32x4 zacc = {0.f, 0.f, 0.f, 0.f};
            zacc = __builtin_amdgcn_mfma_f32_16x16x32_bf16(saf, bandf, zacc, 0, 0, 0);
            float p0 = exp2f(zacc[0]), p1 = exp2f(zacc[1]);
            float p2 = exp2f(zacc[2]), p3 = exp2f(zacc[3]);
            l_part += (p0 + p1) + (p2 + p3);
            uint2 uu;
            uu.x = cvtpk(p0, p1);
            uu.y = cvtpk(p2, p3);
            *(uint2*)((char*)Ps + strow * 128 +
                      (((2 * ct + (kgrp >> 1)) ^ (arow & 7)) << 4) +
                      ((kgrp & 1) << 3)) = uu;
        }
        // pin P-store -> P-read program order (per-wave DS is in-order in HW)
        __builtin_amdgcn_sched_barrier(0);
        // PV (wave-local P reads; hoisted V fragments)
        {
            const char* psb = (const char*)Ps;
            bf16x8 pf0 = *(const bf16x8*)(psb + strow * 128 +
                                          ((kgrp ^ (arow & 7)) << 4));
            bf16x8 pf1 = *(const bf16x8*)(psb + strow * 128 +
                                          (((4 + kgrp) ^ (arow & 7)) << 4));
            #pragma unroll
            for (int dt = 0; dt < 4; ++dt) {
                oacc[dt] = __builtin_amdgcn_mfma_f32_16x16x32_bf16(
                    pf0, vf[dt][0], oacc[dt], 0, 0, 0);
                oacc[dt] = __builtin_amdgcn_mfma_f32_16x16x32_bf16(
                    pf1, vf[dt][1], oacc[dt], 0, 0, 0);
            }
        }
    }

    // finalize row sums (deferred): reduce across the 4 kgrp lane-groups
    l_part += __shfl_xor(l_part, 16);
    l_part += __shfl_xor(l_part, 32);
    if (kgrp == 0) row_l[strow] = l_part;
    __syncthreads();
    float inv[4];
    #pragma unroll
    for (int i = 0; i < 4; ++i) inv[i] = 1.f / row_l[w * 16 + kgrp * 4 + i];
    #pragma unroll
    for (int dt = 0; dt < 4; ++dt) {
        #pragma unroll
        for (int i = 0; i < 4; ++i) {
            size_t t = (size_t)region * 1024 + i0 + w * 16 + kgrp * 4 + i;
            ao[t * 512 + head * 64 + dt * 16 + arow] = f2bf(oacc[dt][i] * inv[i]);
        }
    }
}

// ---------------- Kernel 3: proj GEMM (bf16 MFMA, fp32 out, un-permute) -------------
__global__ __launch_bounds__(256) void proj_kernel(
    const unsigned short* __restrict__ ab, const unsigned short* __restrict__ wb,
    const float* __restrict__ bias, float* __restrict__ out)
{
    __shared__ __align__(16) unsigned short As[128 * 64];
    __shared__ __align__(16) unsigned short Bs[128 * 64];
    const int c0t = blockIdx.x * 128;
    const int t0 = blockIdx.y * 128;
    const int tid = threadIdx.x;
    const int lane = tid & 63, w = tid >> 6;
    const int arow = lane & 15, kgrp = lane >> 4;
    const int wr = w >> 1, wc = w & 1;

    f32x4 acc[4][4];
    #pragma unroll
    for (int m = 0; m < 4; ++m)
        #pragma unroll
        for (int n = 0; n < 4; ++n) {
            f32x4 z = {0.f, 0.f, 0.f, 0.f};
            acc[m][n] = z;
        }

    for (int k0 = 0; k0 < 512; k0 += 64) {
        __syncthreads();
        #pragma unroll
        for (int it = 0; it < 4; ++it) {
            int slot = it * 256 + tid;
            int row = slot >> 3, phys = slot & 7;
            int c8 = phys ^ (row & 7);
            gload16(ab + (size_t)(t0 + row) * 512 + k0 + c8 * 8,
                    &As[(it * 256 + (w << 6)) * 8]);
            gload16(wb + (size_t)(c0t + row) * 512 + k0 + c8 * 8,
                    &Bs[(it * 256 + (w << 6)) * 8]);
        }
        __syncthreads();

        bf16x8 af[4][2], bfr[4][2];
        #pragma unroll
        for (int m = 0; m < 4; ++m) {
            int r = wr * 64 + m * 16 + arow;
            af[m][0] = *(const bf16x8*)&As[r * 64 + ((kgrp ^ (r & 7)) * 8)];
            af[m][1] = *(const bf16x8*)&As[r * 64 + (((4 + kgrp) ^ (r & 7)) * 8)];
        }
        #pragma unroll
        for (int n = 0; n < 4; ++n) {
            int r = wc * 64 + n * 16 + arow;
            bfr[n][0] = *(const bf16x8*)&Bs[r * 64 + ((kgrp ^ (r & 7)) * 8)];
            bfr[n][1] = *(const bf16x8*)&Bs[r * 64 + (((4 + kgrp) ^ (r & 7)) * 8)];
        }
        #pragma unroll
        for (int m = 0; m < 4; ++m)
            #pragma unroll
            for (int n = 0; n < 4; ++n) {
                acc[m][n] = __builtin_amdgcn_mfma_f32_16x16x32_bf16(
                    af[m][0], bfr[n][0], acc[m][n], 0, 0, 0);
                acc[m][n] = __builtin_amdgcn_mfma_f32_16x16x32_bf16(
                    af[m][1], bfr[n][1], acc[m][n], 0, 0, 0);
            }
    }

    #pragma unroll
    for (int n = 0; n < 4; ++n) {
        int cg = c0t + wc * 64 + n * 16 + arow;
        float bi = bias[cg];
        #pragma unroll
        for (int m = 0; m < 4; ++m) {
            int tb = t0 + wr * 64 + m * 16 + kgrp * 4;
            int l0 = l_from_rn(tb >> 10, tb & 1023);
            float* p = out + (size_t)l0 * 512 + cg;
            #pragma unroll
            for (int i = 0; i < 4; ++i)
                p[(size_t)i * 512] = acc[m][n][i] + bi;
        }
    }
}

extern "C" void kernel_launch(void* const* d_in, const int* in_sizes, int n_in,
                              void* d_out, int out_size, void* d_ws, size_t ws_size,
                              hipStream_t stream) {
    const float* x      = (const float*)d_in[0];
    const float* qkv_w  = (const float*)d_in[1];
    const float* qkv_b  = (const float*)d_in[2];
    const float* proj_w = (const float*)d_in[3];
    const float* proj_b = (const float*)d_in[4];
    const float* epeg_w = (const float*)d_in[5];
    const float* epeg_b = (const float*)d_in[6];
    float* out = (float*)d_out;

    const size_t NTOK = (size_t)16384 * 512;
    unsigned short* xb    = (unsigned short*)d_ws;
    unsigned short* wqkv  = xb + NTOK;
    unsigned short* wproj = wqkv + (size_t)1536 * 512;
    unsigned short* qb    = wproj + (size_t)512 * 512;
    unsigned short* kb    = qb + NTOK;
    unsigned short* vtb   = kb + NTOK;
    unsigned short* ao    = vtb + NTOK;

    cast_x_kernel<<<4096, 256, 0, stream>>>(x, xb);
    cast_w_kernel<<<384, 256, 0, stream>>>(qkv_w, wqkv);
    cast_w_kernel<<<128, 256, 0, stream>>>(proj_w, wproj);
    {
        dim3 grid(12, 128);
        qkv_kernel<<<grid, 256, 0, stream>>>(xb, wqkv, qkv_b, qb, kb, vtb);
    }
    {
        dim3 grid(16, 8, 16);
        attn_kernel<<<grid, 256, 0, stream>>>(qb, kb, vtb, epeg_w, epeg_b, ao);
    }
    {
        dim3 grid(4, 128);
        proj_kernel<<<grid, 256, 0, stream>>>(ao, wproj, proj_b, out);
    }
}

// Round 10
// 166.164 us; speedup vs baseline: 1.1586x; 1.0049x over previous
//
#include <hip/hip_runtime.h>

// RegionAttention: bf16 MFMA everywhere; attention uses MFMA for QK, EPEG-conv
// (banded matmul), and PV; no-max softmax in exp2 domain; deferred row-sum.
// R10 = R9 + QBLK 64->128 (staging/barrier/halo cost per work halved) +
// XCD-aware block swizzle (all i-blocks of one (region,head) on one XCD ->
// K/V L2-resident). q is PRE-SCALED by 0.125*log2(e).

using bf16x8 = __attribute__((ext_vector_type(8))) short;
using f32x4  = __attribute__((ext_vector_type(4))) float;

__device__ __forceinline__ unsigned short f2bf(float f) {
    unsigned u = __float_as_uint(f);
    u += 0x7fff + ((u >> 16) & 1);
    return (unsigned short)(u >> 16);
}
__device__ __forceinline__ unsigned cvtpk(float lo, float hi) {
    unsigned r;
    asm("v_cvt_pk_bf16_f32 %0, %1, %2" : "=v"(r) : "v"(lo), "v"(hi));
    return r;
}
__device__ __forceinline__ void gload16(const void* g, void* l) {
    __builtin_amdgcn_global_load_lds(
        (const __attribute__((address_space(1))) void*)g,
        (__attribute__((address_space(3))) void*)l, 16, 0, 0);
}
__device__ __forceinline__ int l_from_rn(int region, int n) {
    int gi = region >> 2, gj = region & 3;
    int a = n >> 5, b = n & 31;
    return ((gi * 32 + a) << 7) + (gj << 5) + b;
}

// ---------------- cast kernels ----------------
__global__ __launch_bounds__(256) void cast_x_kernel(
    const float* __restrict__ x, unsigned short* __restrict__ xb)
{
    int tid = threadIdx.x;
    int t = blockIdx.x * 4 + (tid >> 6);
    int c8 = tid & 63;
    int l = l_from_rn(t >> 10, t & 1023);
    const float* src = x + (size_t)l * 512 + c8 * 8;
    float4 a = *(const float4*)src;
    float4 b = *(const float4*)(src + 4);
    bf16x8 o;
    o[0] = (short)f2bf(a.x); o[1] = (short)f2bf(a.y);
    o[2] = (short)f2bf(a.z); o[3] = (short)f2bf(a.w);
    o[4] = (short)f2bf(b.x); o[5] = (short)f2bf(b.y);
    o[6] = (short)f2bf(b.z); o[7] = (short)f2bf(b.w);
    *(bf16x8*)(xb + (size_t)t * 512 + c8 * 8) = o;
}

__global__ __launch_bounds__(256) void cast_w_kernel(
    const float* __restrict__ w, unsigned short* __restrict__ wb)
{
    int g = blockIdx.x * 256 + threadIdx.x;
    const float* src = w + (size_t)g * 8;
    float4 a = *(const float4*)src;
    float4 b = *(const float4*)(src + 4);
    bf16x8 o;
    o[0] = (short)f2bf(a.x); o[1] = (short)f2bf(a.y);
    o[2] = (short)f2bf(a.z); o[3] = (short)f2bf(a.w);
    o[4] = (short)f2bf(b.x); o[5] = (short)f2bf(b.y);
    o[6] = (short)f2bf(b.z); o[7] = (short)f2bf(b.w);
    *(bf16x8*)(wb + (size_t)g * 8) = o;
}

// ---------------- Kernel 1: QKV GEMM (bf16 MFMA) ----------------
__global__ __launch_bounds__(256) void qkv_kernel(
    const unsigned short* __restrict__ xb, const unsigned short* __restrict__ wb,
    const float* __restrict__ bias, unsigned short* __restrict__ qo,
    unsigned short* __restrict__ ko, unsigned short* __restrict__ vto)
{
    __shared__ __align__(16) unsigned short As[128 * 64];
    __shared__ __align__(16) unsigned short Bs[128 * 64];
    const int c0t = blockIdx.x * 128;
    const int t0 = blockIdx.y * 128;
    const int tid = threadIdx.x;
    const int lane = tid & 63, w = tid >> 6;
    const int arow = lane & 15, kgrp = lane >> 4;
    const int wr = w >> 1, wc = w & 1;

    f32x4 acc[4][4];
    #pragma unroll
    for (int m = 0; m < 4; ++m)
        #pragma unroll
        for (int n = 0; n < 4; ++n) {
            f32x4 z = {0.f, 0.f, 0.f, 0.f};
            acc[m][n] = z;
        }

    for (int k0 = 0; k0 < 512; k0 += 64) {
        __syncthreads();
        #pragma unroll
        for (int it = 0; it < 4; ++it) {
            int slot = it * 256 + tid;
            int row = slot >> 3, phys = slot & 7;
            int c8 = phys ^ (row & 7);
            gload16(xb + (size_t)(t0 + row) * 512 + k0 + c8 * 8,
                    &As[(it * 256 + (w << 6)) * 8]);
            gload16(wb + (size_t)(c0t + row) * 512 + k0 + c8 * 8,
                    &Bs[(it * 256 + (w << 6)) * 8]);
        }
        __syncthreads();

        bf16x8 af[4][2], bfr[4][2];
        #pragma unroll
        for (int m = 0; m < 4; ++m) {
            int r = wr * 64 + m * 16 + arow;
            af[m][0] = *(const bf16x8*)&As[r * 64 + ((kgrp ^ (r & 7)) * 8)];
            af[m][1] = *(const bf16x8*)&As[r * 64 + (((4 + kgrp) ^ (r & 7)) * 8)];
        }
        #pragma unroll
        for (int n = 0; n < 4; ++n) {
            int r = wc * 64 + n * 16 + arow;
            bfr[n][0] = *(const bf16x8*)&Bs[r * 64 + ((kgrp ^ (r & 7)) * 8)];
            bfr[n][1] = *(const bf16x8*)&Bs[r * 64 + (((4 + kgrp) ^ (r & 7)) * 8)];
        }
        #pragma unroll
        for (int m = 0; m < 4; ++m)
            #pragma unroll
            for (int n = 0; n < 4; ++n) {
                acc[m][n] = __builtin_amdgcn_mfma_f32_16x16x32_bf16(
                    af[m][0], bfr[n][0], acc[m][n], 0, 0, 0);
                acc[m][n] = __builtin_amdgcn_mfma_f32_16x16x32_bf16(
                    af[m][1], bfr[n][1], acc[m][n], 0, 0, 0);
            }
    }

    const int s = c0t >> 9;
    const int region = t0 >> 10;
    // q pre-scale: 0.125 (attn scale) * log2(e) (exp2-domain softmax)
    const float qs = (s == 0) ? 0.18033688f : 1.0f;
    #pragma unroll
    for (int n = 0; n < 4; ++n) {
        int cg = c0t + wc * 64 + n * 16 + arow;
        float bi = bias[cg];
        int h = (cg >> 6) & 7, d = cg & 63;
        if (s < 2) {
            unsigned short* dst = (s == 0) ? qo : ko;
            #pragma unroll
            for (int m = 0; m < 4; ++m) {
                int tb = t0 + wr * 64 + m * 16 + kgrp * 4;
                unsigned short* p =
                    dst + ((size_t)(region * 8 + h) * 1024 + (tb & 1023)) * 64 + d;
                #pragma unroll
                for (int i = 0; i < 4; ++i)
                    p[(size_t)i * 64] = f2bf((acc[m][n][i] + bi) * qs);
            }
        } else {
            #pragma unroll
            for (int m = 0; m < 4; ++m) {
                int tb = t0 + wr * 64 + m * 16 + kgrp * 4;
                ushort4 pk;
                pk.x = f2bf(acc[m][n][0] + bi);
                pk.y = f2bf(acc[m][n][1] + bi);
                pk.z = f2bf(acc[m][n][2] + bi);
                pk.w = f2bf(acc[m][n][3] + bi);
                *(ushort4*)(vto + (size_t)(region * 8 + h) * 65536 +
                            (size_t)d * 1024 + (tb & 1023)) = pk;
            }
        }
    }
}

// ---------------- Kernel 2: all-MFMA attention, QBLK=128, q-split waves -----------
__global__ __launch_bounds__(256) void attn_kernel(
    const unsigned short* __restrict__ qg, const unsigned short* __restrict__ kg,
    const unsigned short* __restrict__ vtg, const float* __restrict__ epw,
    const float* __restrict__ epb, unsigned short* __restrict__ ao)
{
    // XCD swizzle: 1024 blocks; all 8 i-blocks of one rh on one XCD
    const int bid = blockIdx.x;
    const int wid = (bid & 7) * 128 + (bid >> 3);
    const int rb = wid & 7;          // i-block (128 q rows)
    const int rh = wid >> 3;         // region*8 + head
    const int head = rh & 7, region = rh >> 3;
    const unsigned short* qb = qg + (size_t)rh * 65536;
    const unsigned short* kb = kg + (size_t)rh * 65536;
    const unsigned short* vb = vtg + (size_t)rh * 65536;
    const int i0 = rb * 128;
    const int tid = threadIdx.x;
    const int lane = tid & 63, w = tid >> 6;
    const int arow = lane & 15, kgrp = lane >> 4;

    __shared__ __align__(16) unsigned short Ks[2][4096];
    __shared__ __align__(16) unsigned short VTs[2][4096];
    __shared__ __align__(16) unsigned char ST2[64 * 304]; // S^T [j][q], 304B rows
    __shared__ __align__(16) unsigned short Ps[128 * 64]; // P [q][j]
    __shared__ float row_l[128];

    char* const st2b = (char*)ST2;
    // zero ST2 pad regions per row: bytes 0..3 (q=-4,-3) and 268..303 (q>=130)
    for (int idx = tid; idx < 640; idx += 256) {
        int j = idx / 10, sl = idx % 10;
        int off = (sl == 0) ? 0 : (264 + sl * 4);
        *(unsigned*)(st2b + j * 304 + off) = 0u;
    }

    // Q fragments: wave owns q in [w*32, w*32+32), two 16-row groups
    bf16x8 qf[2][2];
    #pragma unroll
    for (int m = 0; m < 2; ++m) {
        const unsigned short* p =
            qb + (size_t)(i0 + w * 32 + m * 16 + arow) * 64 + kgrp * 8;
        qf[m][0] = *(const bf16x8*)p;
        qf[m][1] = *(const bf16x8*)(p + 32);
    }
    // halo Q fragment: A-rows 0..3 = q rows {i0-2,i0-1,i0+128,i0+129}, rest zero
    bf16x8 qhf0, qhf1;
    #pragma unroll
    for (int e = 0; e < 8; ++e) { qhf0[e] = 0; qhf1[e] = 0; }
    {
        int gi = (arow < 2) ? (i0 - 2 + arow) : (i0 + 126 + arow);
        if (arow < 4 && gi >= 0 && gi < 1024) {
            const unsigned short* p = qb + (size_t)gi * 64 + kgrp * 8;
            qhf0 = *(const bf16x8*)p;
            qhf1 = *(const bf16x8*)(p + 32);
        }
    }

    // Band B-fragment (constant): B[k][n=arow] = cwt[k-n-2], k = kgrp*8+e
    bf16x8 bandf;
    {
        float cwt[5];
        #pragma unroll
        for (int t = 0; t < 5; ++t) cwt[t] = epw[head * 5 + t];
        cwt[2] += 1.0f;   // identity (direct S) term
        #pragma unroll
        for (int e = 0; e < 8; ++e) {
            int c = kgrp * 8 + e - arow - 2;
            float v = 0.f;
            v = (c == 0) ? cwt[0] : v;
            v = (c == 1) ? cwt[1] : v;
            v = (c == 2) ? cwt[2] : v;
            v = (c == 3) ? cwt[3] : v;
            v = (c == 4) ? cwt[4] : v;
            bandf[e] = (short)f2bf(v);
        }
    }

    f32x4 oacc[2][4];
    #pragma unroll
    for (int m = 0; m < 2; ++m)
        #pragma unroll
        for (int dt = 0; dt < 4; ++dt) {
            f32x4 z = {0.f, 0.f, 0.f, 0.f};
            oacc[m][dt] = z;
        }
    float lp[2] = {0.f, 0.f};

    auto stage = [&](int jt, int buf) {
        const int j0 = jt * 64;
        #pragma unroll
        for (int it = 0; it < 2; ++it) {
            int q_ = (it * 4 + w) * 64 + lane;
            int row = q_ >> 3, phys = q_ & 7, c8 = phys ^ (row & 7);
            gload16(kb + (size_t)(j0 + row) * 64 + c8 * 8,
                    &Ks[buf][(it * 4 + w) * 512]);
            gload16(vb + (size_t)row * 1024 + j0 + c8 * 8,
                    &VTs[buf][(it * 4 + w) * 512]);
        }
    };

    stage(0, 0);

    for (int jt = 0; jt < 16; ++jt) {
        const int cur = jt & 1;
        __syncthreads();   // staged tile landed; ST2/Ps reads of prev tile done
        if (jt < 15) stage(jt + 1, cur ^ 1);

        const unsigned short* Kc = &Ks[cur][0];
        const unsigned short* Vc = &VTs[cur][0];

        // hoisted V fragments (valid post-barrier; overlap QK/S^T phase)
        bf16x8 vf[4][2];
        #pragma unroll
        for (int dt = 0; dt < 4; ++dt) {
            int drow = dt * 16 + arow;
            vf[dt][0] = *(const bf16x8*)&Vc[drow * 64 + ((kgrp ^ (drow & 7)) * 8)];
            vf[dt][1] = *(const bf16x8*)&Vc[drow * 64 + (((4 + kgrp) ^ (drow & 7)) * 8)];
        }

        // QK -> S^T bf16: wave w writes q cols [w*32, w*32+32) of all 64 j rows
        #pragma unroll
        for (int ct = 0; ct < 4; ++ct) {
            int krow = ct * 16 + arow;
            bf16x8 kf0 = *(const bf16x8*)&Kc[krow * 64 + ((kgrp ^ (krow & 7)) * 8)];
            bf16x8 kf1 = *(const bf16x8*)&Kc[krow * 64 + (((4 + kgrp) ^ (krow & 7)) * 8)];
            char* const srow = st2b + krow * 304;
            #pragma unroll
            for (int m = 0; m < 2; ++m) {
                f32x4 sacc = {0.f, 0.f, 0.f, 0.f};
                sacc = __builtin_amdgcn_mfma_f32_16x16x32_bf16(qf[m][0], kf0, sacc, 0, 0, 0);
                sacc = __builtin_amdgcn_mfma_f32_16x16x32_bf16(qf[m][1], kf1, sacc, 0, 0, 0);
                uint2 uu;
                uu.x = cvtpk(sacc[0], sacc[1]);
                uu.y = cvtpk(sacc[2], sacc[3]);
                *(uint2*)(srow + 8 + w * 64 + m * 32 + kgrp * 8) = uu;
            }
            if (ct == w) {   // halo rows for this wave's 16-j group
                f32x4 hacc = {0.f, 0.f, 0.f, 0.f};
                hacc = __builtin_amdgcn_mfma_f32_16x16x32_bf16(qhf0, kf0, hacc, 0, 0, 0);
                hacc = __builtin_amdgcn_mfma_f32_16x16x32_bf16(qhf1, kf1, hacc, 0, 0, 0);
                if (kgrp == 0) {
                    *(unsigned*)(srow + 4)   = cvtpk(hacc[0], hacc[1]);   // q=-2,-1
                    *(unsigned*)(srow + 264) = cvtpk(hacc[2], hacc[3]);   // q=128,129
                }
            }
        }
        // S^T visible to all waves; prefetch stays in flight (no vmcnt drain)
        asm volatile("s_waitcnt lgkmcnt(0)\n\ts_barrier" ::: "memory");

        // conv via banded MFMA -> p=exp2 -> pack -> Ps
        #pragma unroll
        for (int ct = 0; ct < 4; ++ct) {
            #pragma unroll
            for (int m = 0; m < 2; ++m) {
                bf16x8 saf = *(const bf16x8*)(st2b + (ct * 16 + arow) * 304 +
                                              w * 64 + m * 32 + kgrp * 16);
                f32x4 zacc = {0.f, 0.f, 0.f, 0.f};
                zacc = __builtin_amdgcn_mfma_f32_16x16x32_bf16(saf, bandf, zacc, 0, 0, 0);
                float p0 = exp2f(zacc[0]), p1 = exp2f(zacc[1]);
                float p2 = exp2f(zacc[2]), p3 = exp2f(zacc[3]);
                lp[m] += (p0 + p1) + (p2 + p3);
                uint2 uu;
                uu.x = cvtpk(p0, p1);
                uu.y = cvtpk(p2, p3);
                *(uint2*)((char*)Ps + (w * 32 + m * 16 + arow) * 128 +
                          (((2 * ct + (kgrp >> 1)) ^ (arow & 7)) << 4) +
                          ((kgrp & 1) << 3)) = uu;
            }
        }
        // pin P-store -> P-read program order (per-wave DS is in-order in HW)
        __builtin_amdgcn_sched_barrier(0);
        // PV (wave-local P reads; hoisted V fragments)
        #pragma unroll
        for (int m = 0; m < 2; ++m) {
            const char* prow = (const char*)Ps + (w * 32 + m * 16 + arow) * 128;
            bf16x8 pf0 = *(const bf16x8*)(prow + ((kgrp ^ (arow & 7)) << 4));
            bf16x8 pf1 = *(const bf16x8*)(prow + (((4 + kgrp) ^ (arow & 7)) << 4));
            #pragma unroll
            for (int dt = 0; dt < 4; ++dt) {
                oacc[m][dt] = __builtin_amdgcn_mfma_f32_16x16x32_bf16(
                    pf0, vf[dt][0], oacc[m][dt], 0, 0, 0);
                oacc[m][dt] = __builtin_amdgcn_mfma_f32_16x16x32_bf16(
                    pf1, vf[dt][1], oacc[m][dt], 0, 0, 0);
            }
        }
    }

    // finalize row sums (deferred): reduce across the 4 kgrp lane-groups
    #pragma unroll
    for (int m = 0; m < 2; ++m) {
        float s = lp[m];
        s += __shfl_xor(s, 16);
        s += __shfl_xor(s, 32);
        if (kgrp == 0) row_l[w * 32 + m * 16 + arow] = s;
    }
    __syncthreads();
    #pragma unroll
    for (int m = 0; m < 2; ++m) {
        float inv[4];
        #pragma unroll
        for (int i = 0; i < 4; ++i)
            inv[i] = 1.f / row_l[w * 32 + m * 16 + kgrp * 4 + i];
        #pragma unroll
        for (int dt = 0; dt < 4; ++dt) {
            #pragma unroll
            for (int i = 0; i < 4; ++i) {
                size_t t = (size_t)region * 1024 + i0 + w * 32 + m * 16 + kgrp * 4 + i;
                ao[t * 512 + head * 64 + dt * 16 + arow] = f2bf(oacc[m][dt][i] * inv[i]);
            }
        }
    }
}

// ---------------- Kernel 3: proj GEMM (bf16 MFMA, fp32 out, un-permute) -------------
__global__ __launch_bounds__(256) void proj_kernel(
    const unsigned short* __restrict__ ab, const unsigned short* __restrict__ wb,
    const float* __restrict__ bias, float* __restrict__ out)
{
    __shared__ __align__(16) unsigned short As[128 * 64];
    __shared__ __align__(16) unsigned short Bs[128 * 64];
    const int c0t = blockIdx.x * 128;
    const int t0 = blockIdx.y * 128;
    const int tid = threadIdx.x;
    const int lane = tid & 63, w = tid >> 6;
    const int arow = lane & 15, kgrp = lane >> 4;
    const int wr = w >> 1, wc = w & 1;

    f32x4 acc[4][4];
    #pragma unroll
    for (int m = 0; m < 4; ++m)
        #pragma unroll
        for (int n = 0; n < 4; ++n) {
            f32x4 z = {0.f, 0.f, 0.f, 0.f};
            acc[m][n] = z;
        }

    for (int k0 = 0; k0 < 512; k0 += 64) {
        __syncthreads();
        #pragma unroll
        for (int it = 0; it < 4; ++it) {
            int slot = it * 256 + tid;
            int row = slot >> 3, phys = slot & 7;
            int c8 = phys ^ (row & 7);
            gload16(ab + (size_t)(t0 + row) * 512 + k0 + c8 * 8,
                    &As[(it * 256 + (w << 6)) * 8]);
            gload16(wb + (size_t)(c0t + row) * 512 + k0 + c8 * 8,
                    &Bs[(it * 256 + (w << 6)) * 8]);
        }
        __syncthreads();

        bf16x8 af[4][2], bfr[4][2];
        #pragma unroll
        for (int m = 0; m < 4; ++m) {
            int r = wr * 64 + m * 16 + arow;
            af[m][0] = *(const bf16x8*)&As[r * 64 + ((kgrp ^ (r & 7)) * 8)];
            af[m][1] = *(const bf16x8*)&As[r * 64 + (((4 + kgrp) ^ (r & 7)) * 8)];
        }
        #pragma unroll
        for (int n = 0; n < 4; ++n) {
            int r = wc * 64 + n * 16 + arow;
            bfr[n][0] = *(const bf16x8*)&Bs[r * 64 + ((kgrp ^ (r & 7)) * 8)];
            bfr[n][1] = *(const bf16x8*)&Bs[r * 64 + (((4 + kgrp) ^ (r & 7)) * 8)];
        }
        #pragma unroll
        for (int m = 0; m < 4; ++m)
            #pragma unroll
            for (int n = 0; n < 4; ++n) {
                acc[m][n] = __builtin_amdgcn_mfma_f32_16x16x32_bf16(
                    af[m][0], bfr[n][0], acc[m][n], 0, 0, 0);
                acc[m][n] = __builtin_amdgcn_mfma_f32_16x16x32_bf16(
                    af[m][1], bfr[n][1], acc[m][n], 0, 0, 0);
            }
    }

    #pragma unroll
    for (int n = 0; n < 4; ++n) {
        int cg = c0t + wc * 64 + n * 16 + arow;
        float bi = bias[cg];
        #pragma unroll
        for (int m = 0; m < 4; ++m) {
            int tb = t0 + wr * 64 + m * 16 + kgrp * 4;
            int l0 = l_from_rn(tb >> 10, tb & 1023);
            float* p = out + (size_t)l0 * 512 + cg;
            #pragma unroll
            for (int i = 0; i < 4; ++i)
                p[(size_t)i * 512] = acc[m][n][i] + bi;
        }
    }
}

extern "C" void kernel_launch(void* const* d_in, const int* in_sizes, int n_in,
                              void* d_out, int out_size, void* d_ws, size_t ws_size,
                              hipStream_t stream) {
    const float* x      = (const float*)d_in[0];
    const float* qkv_w  = (const float*)d_in[1];
    const float* qkv_b  = (const float*)d_in[2];
    const float* proj_w = (const float*)d_in[3];
    const float* proj_b = (const float*)d_in[4];
    const float* epeg_w = (const float*)d_in[5];
    const float* epeg_b = (const float*)d_in[6];
    float* out = (float*)d_out;

    const size_t NTOK = (size_t)16384 * 512;
    unsigned short* xb    = (unsigned short*)d_ws;
    unsigned short* wqkv  = xb + NTOK;
    unsigned short* wproj = wqkv + (size_t)1536 * 512;
    unsigned short* qb    = wproj + (size_t)512 * 512;
    unsigned short* kb    = qb + NTOK;
    unsigned short* vtb   = kb + NTOK;
    unsigned short* ao    = vtb + NTOK;

    cast_x_kernel<<<4096, 256, 0, stream>>>(x, xb);
    cast_w_kernel<<<384, 256, 0, stream>>>(qkv_w, wqkv);
    cast_w_kernel<<<128, 256, 0, stream>>>(proj_w, wproj);
    {
        dim3 grid(12, 128);
        qkv_kernel<<<grid, 256, 0, stream>>>(xb, wqkv, qkv_b, qb, kb, vtb);
    }
    attn_kernel<<<1024, 256, 0, stream>>>(qb, kb, vtb, epeg_w, epeg_b, ao);
    {
        dim3 grid(4, 128);
        proj_kernel<<<grid, 256, 0, stream>>>(ao, wproj, proj_b, out);
    }
}